// Round 13
// baseline (274.079 us; speedup 1.0000x reference)
//
#include <hip/hip_runtime.h>
#include <hip/hip_bf16.h>

typedef __attribute__((ext_vector_type(8))) short bf16x8;
typedef __attribute__((ext_vector_type(4))) short bf16x4;
typedef __attribute__((ext_vector_type(4))) float f32x4;

#define MFMA32(a,b,c) __builtin_amdgcn_mfma_f32_16x16x32_bf16(a,b,c,0,0,0)

#if __has_builtin(__builtin_amdgcn_mfma_f32_16x16x16bf16_1k)
#define MFMA16(a,b,c) __builtin_amdgcn_mfma_f32_16x16x16bf16_1k(a,b,c,0,0,0)
#else
static __device__ __forceinline__ f32x4 mfma16_asm(bf16x4 a, bf16x4 b, f32x4 c){
  asm volatile("v_mfma_f32_16x16x16_bf16 %0, %1, %2, %0" : "+v"(c) : "v"(a), "v"(b));
  return c;
}
#define MFMA16(a,b,c) mfma16_asm(a,b,c)
#endif

#define NEGV -65504.0f

__device__ __forceinline__ unsigned short f2bf(float f){
  union { float f; unsigned u; } x; x.f = f;
  unsigned r = x.u + 0x7fffu + ((x.u >> 16) & 1u);
  return (unsigned short)(r >> 16);
}

__device__ __forceinline__ unsigned cvtpk(float a, float b){
  unsigned r;
  asm volatile("v_cvt_pk_bf16_f32 %0, %1, %2" : "=v"(r) : "v"(a), "v"(b));
  return r;   // a -> low 16, b -> high 16
}

// ------- fused: fp32->bf16 convert (x, W_qkv, W_proj) + mask int32->bits -------
// blocks [0,8448): convert;  blocks [8448,10496): mask ballot
__global__ __launch_bounds__(256) void cvt_mask(
    const float* __restrict__ x, const float* __restrict__ wq,
    const float* __restrict__ wp, unsigned short* __restrict__ out,
    const int* __restrict__ m, unsigned long long* __restrict__ mb){
  int bid = blockIdx.x;
  if (bid < 8448) {
    int i = bid * 256 + threadIdx.x;
    const float* src; int j;
    if (i < 1572864)      { src = x;  j = i; }
    else if (i < 2015232) { src = wq; j = i - 1572864; }
    else                  { src = wp; j = i - 2015232; }
    float4 f = ((const float4*)src)[j];
    ushort4 u;
    u.x = f2bf(f.x); u.y = f2bf(f.y); u.z = f2bf(f.z); u.w = f2bf(f.w);
    ((ushort4*)out)[i] = u;
  } else {
    int gw = ((bid - 8448) * 256 + threadIdx.x) >> 6;   // wave id 0..8191
    int lane = threadIdx.x & 63;
#pragma unroll
    for (int stp = 0; stp < 16; ++stp) {
      size_t base = ((size_t)gw * 16 + stp) * 64;
      int v = m[base + lane];
      unsigned long long bbm = __ballot(v != 0);
      if (lane == 0) mb[base >> 6] = bbm;
    }
  }
}

// ---------------- LDS-staged QKV GEMM: X[8192,768] @ W[2304,768]^T + b ----------
__global__ __launch_bounds__(256) void gemm_qkv(
    const unsigned short* __restrict__ X,
    const unsigned short* __restrict__ W,
    const float* __restrict__ bias,
    unsigned short* __restrict__ Qd,
    unsigned short* __restrict__ Kd,
    unsigned short* __restrict__ Vd)
{
  __shared__ unsigned short As[128*40];
  __shared__ unsigned short Bs[128*40];
  const int K = 768;
  int tid = threadIdx.x;
  int bm = blockIdx.x & 63;
  int bn = blockIdx.x >> 6;
  int wave = tid >> 6, lane = tid & 63;
  int lo = lane & 15, g = lane >> 4;
  int wr = (wave >> 1) * 64, wc = (wave & 1) * 64;
  int row0 = bm * 128, col0 = bn * 128;

  int sr = tid >> 1;
  int sc = (tid & 1) * 16;
  const unsigned short* gA = X + (size_t)(row0 + sr) * K + sc;
  const unsigned short* gB = W + (size_t)(col0 + sr) * K + sc;
  unsigned short* sA = &As[sr * 40 + sc];
  unsigned short* sB = &Bs[sr * 40 + sc];

  f32x4 acc[4][4] = {};
  for (int k0 = 0; k0 < K; k0 += 32) {
    bf16x8 a0 = *(const bf16x8*)(gA + k0);
    bf16x8 a1 = *(const bf16x8*)(gA + k0 + 8);
    bf16x8 b0 = *(const bf16x8*)(gB + k0);
    bf16x8 b1 = *(const bf16x8*)(gB + k0 + 8);
    __syncthreads();
    *(bf16x8*)(sA)     = a0;
    *(bf16x8*)(sA + 8) = a1;
    *(bf16x8*)(sB)     = b0;
    *(bf16x8*)(sB + 8) = b1;
    __syncthreads();
    bf16x8 af[4], bf[4];
#pragma unroll
    for (int i = 0; i < 4; ++i) af[i] = *(const bf16x8*)&As[(wr + i*16 + lo)*40 + g*8];
#pragma unroll
    for (int i = 0; i < 4; ++i) bf[i] = *(const bf16x8*)&Bs[(wc + i*16 + lo)*40 + g*8];
#pragma unroll
    for (int mi = 0; mi < 4; ++mi)
#pragma unroll
      for (int ni = 0; ni < 4; ++ni)
        acc[mi][ni] = MFMA32(af[mi], bf[ni], acc[mi][ni]);
  }
  int orow0 = row0 + wr, ocol0 = col0 + wc;
#pragma unroll
  for (int ni = 0; ni < 4; ++ni) {
    int col = ocol0 + ni*16 + lo;
    float bc = bias[col];
    int which = col / 768;
    int rem = col - which * 768;
    int h = rem >> 6, d = rem & 63;
    unsigned short* dst = (which == 0) ? Qd : (which == 1) ? Kd : Vd;
    float scale = (which == 0) ? 0.125f : 1.0f;
#pragma unroll
    for (int mi = 0; mi < 4; ++mi) {
#pragma unroll
      for (int r = 0; r < 4; ++r) {
        int row = orow0 + mi*16 + g*4 + r;
        int bb = row >> 10, n = row & 1023;
        dst[(((size_t)bb*12 + h)*1024 + n)*64 + d] = f2bf((acc[mi][ni][r] + bc) * scale);
      }
    }
  }
}

// ---------------- V transpose: [96][1024][64] -> [96][64][1024] ----------------
__global__ __launch_bounds__(256) void vtrans(const unsigned short* __restrict__ V,
                                              unsigned short* __restrict__ Vt){
  __shared__ unsigned short t[64][72];
  int bh = blockIdx.y;
  int n0 = blockIdx.x * 64;
  int tid = threadIdx.x;
  int nl = tid >> 2;
  int dq = (tid & 3) * 16;
  const unsigned short* src = V + ((size_t)bh*1024 + n0 + nl)*64 + dq;
  bf16x8 a0 = *(const bf16x8*)(src);
  bf16x8 a1 = *(const bf16x8*)(src + 8);
  *(bf16x8*)&t[nl][dq]     = a0;
  *(bf16x8*)&t[nl][dq + 8] = a1;
  __syncthreads();
  int d  = tid >> 2;
  int nq = (tid & 3) * 16;
  union { unsigned short s[16]; bf16x8 v[2]; } pk;
#pragma unroll
  for (int j = 0; j < 16; ++j) pk.s[j] = t[nq + j][d];
  unsigned short* dst = Vt + ((size_t)bh*64 + d)*1024 + n0 + nq;
  *(bf16x8*)(dst)     = pk.v[0];
  *(bf16x8*)(dst + 8) = pk.v[1];
}

// ---------------- fused attention core (R7 body, XCD-colocated grid) -----------
// grid (96 bh, 8 qblocks): linear wg id = bh + 96*qblock, so all 8 q-blocks of
// one bh satisfy id % 8 == bh % 8 -> same XCD -> K/V stage loads hit that XCD's
// L2 after the first fetch (stage latency is what the barrier waits on).
__global__ __launch_bounds__(512, 4) void attn_kernel(
    const unsigned short* __restrict__ Qd,
    const unsigned short* __restrict__ Kd,
    const unsigned short* __restrict__ Vt,     // [96][64][1024]
    const float* __restrict__ bias,            // [12,1024,1024] fp32
    const unsigned* __restrict__ maskbits,     // [8*1024][32] u32 words
    float* __restrict__ out1,                  // [96,1024,1024] fp32
    unsigned short* __restrict__ ctx)          // [8192,768] bf16
{
  __shared__ char lds[32768];
  const int N = 1024, D = 64;
  int y = blockIdx.x;                          // bh packing: y = h*8 + b
  int h = y >> 3, bb = y & 7;
  int bh = bb * 12 + h;
  int tid = threadIdx.x;
  int wave = tid >> 6, lane = tid & 63;
  int lo = lane & 15, g = lane >> 4;
  int qrow = blockIdx.y * 128 + wave * 16 + lo;

  const size_t qoff = ((size_t)bh * N + qrow) * D;
  bf16x8 qf0 = *(const bf16x8*)(Qd + qoff + g*8);
  bf16x8 qf1 = *(const bf16x8*)(Qd + qoff + 32 + g*8);

  const float* bias_row = bias + ((size_t)h * N + qrow) * N;
  const unsigned* mrow  = maskbits + ((size_t)bb * N + qrow) * 32;
  float* out_row        = out1 + ((size_t)bh * N + qrow) * N;

  int o  = tid * 16;
  int sw = o ^ (((o >> 7) & 7) << 4);
  const char* kbase = (const char*)(Kd + (size_t)bh * N * D);
  const char* vbase = (const char*)(Vt + (size_t)bh * D * N);
  const char* ksrc  = kbase + sw;                           // + kv*128 per tile
  const char* vsrc  = vbase + (o >> 7) * 2048 + (sw & 127); // + kv*2 per tile
  int wbase = wave << 10;

#define STAGE(buf, kv) do { \
    __builtin_amdgcn_global_load_lds( \
      (const __attribute__((address_space(1))) unsigned*)(ksrc + (size_t)(kv)*128), \
      (__attribute__((address_space(3))) unsigned*)(lds + (buf)*8192 + wbase), 16, 0, 0); \
    __builtin_amdgcn_global_load_lds( \
      (const __attribute__((address_space(1))) unsigned*)(vsrc + (size_t)(kv)*2), \
      (__attribute__((address_space(3))) unsigned*)(lds + 16384 + (buf)*8192 + wbase), 16, 0, 0); \
  } while (0)

#define SWZ(lb) ((lb) ^ ((((lb) >> 7) & 7) << 4))

  float m_run = -INFINITY, l_part = 0.0f;
  f32x4 oacc[4] = {};   // O^T: lane holds q=lo, d = c*16 + g*4 + reg

  STAGE(0, 0);
  __syncthreads();
  int cur = 0;

  for (int it = 0; it < 16; ++it) {
    int kv = it * 64;
    if (it < 15) STAGE(cur ^ 1, kv + 64);
    __builtin_amdgcn_sched_barrier(0);

    unsigned mw0 = mrow[it*2];
    unsigned mw1 = mrow[it*2 + 1];

    f32x4 s[4];
    __builtin_amdgcn_s_setprio(1);
#pragma unroll
    for (int sub = 0; sub < 4; ++sub) {
      int lbr = (sub*16 + lo) * 128 + g*16;
      bf16x8 k0 = *(const bf16x8*)(lds + cur*8192 + SWZ(lbr));
      bf16x8 k1 = *(const bf16x8*)(lds + cur*8192 + SWZ(lbr + 64));
      f32x4 t = {};
      t = MFMA32(k0, qf0, t);
      t = MFMA32(k1, qf1, t);
      s[sub] = t;
    }
    __builtin_amdgcn_s_setprio(0);

    float sp[16];
#pragma unroll
    for (int sub = 0; sub < 4; ++sub) {
      f32x4 bi = *(const f32x4*)(bias_row + kv + sub*16 + g*4);
      unsigned mw = (sub < 2) ? mw0 : mw1;
      int sh = (sub & 1) * 16 + g * 4;
#pragma unroll
      for (int r = 0; r < 4; ++r)
        sp[sub*4+r] = (((mw >> (sh + r)) & 1u) ? NEGV : s[sub][r]) + bi[r];
      f32x4 ov;
      ov[0] = sp[sub*4]; ov[1] = sp[sub*4+1]; ov[2] = sp[sub*4+2]; ov[3] = sp[sub*4+3];
      __builtin_nontemporal_store(ov, (f32x4*)(out_row + kv + sub*16 + g*4));
    }

    float lmax = sp[0];
#pragma unroll
    for (int i = 1; i < 16; ++i) lmax = fmaxf(lmax, sp[i]);
    if (!__all(lmax <= m_run + 8.0f)) {
      float tmax = fmaxf(lmax, __shfl_xor(lmax, 16));
      tmax = fmaxf(tmax, __shfl_xor(tmax, 32));
      float mnew = fmaxf(m_run, tmax);
      float alpha = __expf(m_run - mnew);
      l_part *= alpha;
#pragma unroll
      for (int c = 0; c < 4; ++c) {
        oacc[c][0] *= alpha; oacc[c][1] *= alpha;
        oacc[c][2] *= alpha; oacc[c][3] *= alpha;
      }
      m_run = mnew;
    }
    float lsum = 0.0f;
#pragma unroll
    for (int i = 0; i < 16; ++i) { sp[i] = __expf(sp[i] - m_run); lsum += sp[i]; }
    l_part += lsum;

    union { unsigned u[2]; bf16x4 hh; } pk[4];
#pragma unroll
    for (int ks = 0; ks < 4; ++ks) {
      pk[ks].u[0] = cvtpk(sp[ks*4],   sp[ks*4+1]);
      pk[ks].u[1] = cvtpk(sp[ks*4+2], sp[ks*4+3]);
    }

    __builtin_amdgcn_s_setprio(1);
#pragma unroll
    for (int ks = 0; ks < 4; ++ks)
#pragma unroll
      for (int c = 0; c < 4; ++c) {
        int lbv = (c*16 + lo) * 128 + ks*32 + g*8;
        bf16x4 vf = *(const bf16x4*)(lds + 16384 + cur*8192 + SWZ(lbv));
        oacc[c] = MFMA16(vf, pk[ks].hh, oacc[c]);
      }
    __builtin_amdgcn_s_setprio(0);

    cur ^= 1;
    // counted barrier: retire everything except the <=4 newest (the NT stores).
    __builtin_amdgcn_sched_barrier(0);
    asm volatile("s_waitcnt vmcnt(4)" ::: "memory");
    __builtin_amdgcn_s_barrier();
  }

  l_part += __shfl_xor(l_part, 16);
  l_part += __shfl_xor(l_part, 32);
  float inv = 1.0f / l_part;

  size_t crow = ((size_t)bb * N + qrow) * 768 + h * 64;
#pragma unroll
  for (int c = 0; c < 4; ++c) {
    ushort4 u;
    u.x = f2bf(oacc[c][0] * inv);
    u.y = f2bf(oacc[c][1] * inv);
    u.z = f2bf(oacc[c][2] * inv);
    u.w = f2bf(oacc[c][3] * inv);
    *(ushort4*)(ctx + crow + c*16 + g*4) = u;
  }
#undef STAGE
#undef SWZ
}

// ---------------- LDS-staged proj GEMM: ctx[8192,768] @ Wp[768,768]^T + b ------
__global__ __launch_bounds__(256) void gemm_proj(
    const unsigned short* __restrict__ X,
    const unsigned short* __restrict__ W,
    const float* __restrict__ bias,
    float* __restrict__ out)
{
  __shared__ unsigned short As[128*40];
  __shared__ unsigned short Bs[128*40];
  const int K = 768;
  int tid = threadIdx.x;
  int bm = blockIdx.x & 63;
  int bn = blockIdx.x >> 6;
  int wave = tid >> 6, lane = tid & 63;
  int lo = lane & 15, g = lane >> 4;
  int wr = (wave >> 1) * 64, wc = (wave & 1) * 64;
  int row0 = bm * 128, col0 = bn * 128;

  int sr = tid >> 1;
  int sc = (tid & 1) * 16;
  const unsigned short* gA = X + (size_t)(row0 + sr) * K + sc;
  const unsigned short* gB = W + (size_t)(col0 + sr) * K + sc;
  unsigned short* sA = &As[sr * 40 + sc];
  unsigned short* sB = &Bs[sr * 40 + sc];

  f32x4 acc[4][4] = {};
  for (int k0 = 0; k0 < K; k0 += 32) {
    bf16x8 a0 = *(const bf16x8*)(gA + k0);
    bf16x8 a1 = *(const bf16x8*)(gA + k0 + 8);
    bf16x8 b0 = *(const bf16x8*)(gB + k0);
    bf16x8 b1 = *(const bf16x8*)(gB + k0 + 8);
    __syncthreads();
    *(bf16x8*)(sA)     = a0;
    *(bf16x8*)(sA + 8) = a1;
    *(bf16x8*)(sB)     = b0;
    *(bf16x8*)(sB + 8) = b1;
    __syncthreads();
    bf16x8 af[4], bf[4];
#pragma unroll
    for (int i = 0; i < 4; ++i) af[i] = *(const bf16x8*)&As[(wr + i*16 + lo)*40 + g*8];
#pragma unroll
    for (int i = 0; i < 4; ++i) bf[i] = *(const bf16x8*)&Bs[(wc + i*16 + lo)*40 + g*8];
#pragma unroll
    for (int mi = 0; mi < 4; ++mi)
#pragma unroll
      for (int ni = 0; ni < 4; ++ni)
        acc[mi][ni] = MFMA32(af[mi], bf[ni], acc[mi][ni]);
  }
  int orow0 = row0 + wr, ocol0 = col0 + wc;
#pragma unroll
  for (int ni = 0; ni < 4; ++ni) {
    int col = ocol0 + ni*16 + lo;
    float bc = bias[col];
#pragma unroll
    for (int mi = 0; mi < 4; ++mi) {
#pragma unroll
      for (int r = 0; r < 4; ++r) {
        int row = orow0 + mi*16 + g*4 + r;
        out[(size_t)row * 768 + col] = acc[mi][ni][r] + bc;
      }
    }
  }
}

extern "C" void kernel_launch(void* const* d_in, const int* in_sizes, int n_in,
                              void* d_out, int out_size, void* d_ws, size_t ws_size,
                              hipStream_t stream) {
  const float* x            = (const float*)d_in[0];
  const float* rel_pos_bias = (const float*)d_in[1];
  const int* mask           = (const int*)d_in[2];
  const float* Wqkv         = (const float*)d_in[3];
  const float* bqkv         = (const float*)d_in[4];
  const float* Wproj        = (const float*)d_in[5];
  const float* bproj        = (const float*)d_in[6];

  float* out0 = (float*)d_out;                         // [8,1024,768]
  float* out1 = out0 + (size_t)8 * 1024 * 768;         // [8,12,1024,1024]

  char* ws = (char*)d_ws;
  unsigned short* xb  = (unsigned short*)(ws);            // dead after gemm_qkv -> Vt
  unsigned short* wqb = (unsigned short*)(ws + 12582912);
  unsigned short* wpb = (unsigned short*)(ws + 16121856);
  unsigned short* Qb  = (unsigned short*)(ws + 17301504);
  unsigned short* Kb  = (unsigned short*)(ws + 29884416);
  unsigned short* Vb  = (unsigned short*)(ws + 42467328);
  unsigned short* ctx = (unsigned short*)(ws + 55050240);
  unsigned short* Vtb = xb;
  unsigned long long* mbits = (unsigned long long*)(ws + 67633152); // 1 MB

  cvt_mask<<<10496, 256, 0, stream>>>(x, Wqkv, Wproj, xb, mask, mbits);

  gemm_qkv<<<1152, 256, 0, stream>>>(xb, wqb, bqkv, Qb, Kb, Vb);

  vtrans<<<dim3(16, 96), 256, 0, stream>>>(Vb, Vtb);

  attn_kernel<<<dim3(96, 8), 512, 0, stream>>>(Qb, Kb, Vtb, rel_pos_bias,
                                               (const unsigned*)mbits, out1, ctx);

  gemm_proj<<<384, 256, 0, stream>>>(ctx, wpb, bproj, out0);
}

// Round 14
// 233.400 us; speedup vs baseline: 1.1743x; 1.1743x over previous
//
#include <hip/hip_runtime.h>
#include <hip/hip_bf16.h>

typedef __attribute__((ext_vector_type(8))) short bf16x8;
typedef __attribute__((ext_vector_type(4))) short bf16x4;
typedef __attribute__((ext_vector_type(4))) float f32x4;

#define MFMA32(a,b,c) __builtin_amdgcn_mfma_f32_16x16x32_bf16(a,b,c,0,0,0)

#if __has_builtin(__builtin_amdgcn_mfma_f32_16x16x16bf16_1k)
#define MFMA16(a,b,c) __builtin_amdgcn_mfma_f32_16x16x16bf16_1k(a,b,c,0,0,0)
#else
static __device__ __forceinline__ f32x4 mfma16_asm(bf16x4 a, bf16x4 b, f32x4 c){
  asm volatile("v_mfma_f32_16x16x16_bf16 %0, %1, %2, %0" : "+v"(c) : "v"(a), "v"(b));
  return c;
}
#define MFMA16(a,b,c) mfma16_asm(a,b,c)
#endif

#define NEGV -65504.0f

__device__ __forceinline__ unsigned short f2bf(float f){
  union { float f; unsigned u; } x; x.f = f;
  unsigned r = x.u + 0x7fffu + ((x.u >> 16) & 1u);
  return (unsigned short)(r >> 16);
}

__device__ __forceinline__ unsigned cvtpk(float a, float b){
  unsigned r;
  asm volatile("v_cvt_pk_bf16_f32 %0, %1, %2" : "=v"(r) : "v"(a), "v"(b));
  return r;   // a -> low 16, b -> high 16
}

// ---------------- fused fp32 -> bf16 convert for x, W_qkv, W_proj ----------------
__global__ void cvt_all(const float* __restrict__ x, const float* __restrict__ wq,
                        const float* __restrict__ wp, unsigned short* __restrict__ out){
  int i = blockIdx.x * 256 + threadIdx.x;
  const float* src; int j;
  if (i < 1572864)      { src = x;  j = i; }
  else if (i < 2015232) { src = wq; j = i - 1572864; }
  else                  { src = wp; j = i - 2015232; }
  float4 f = ((const float4*)src)[j];
  ushort4 u;
  u.x = f2bf(f.x); u.y = f2bf(f.y); u.z = f2bf(f.z); u.w = f2bf(f.w);
  ((ushort4*)out)[i] = u;
}

// ---------------- mask int32 -> bitmask (1 bit per element) ----------------
__global__ __launch_bounds__(256) void mask_to_bits(const int* __restrict__ m,
                                                    unsigned long long* __restrict__ out){
  int gw = (blockIdx.x * 256 + threadIdx.x) >> 6;
  int lane = threadIdx.x & 63;
#pragma unroll
  for (int stp = 0; stp < 16; ++stp) {
    size_t base = ((size_t)gw * 16 + stp) * 64;
    int v = m[base + lane];
    unsigned long long bb = __ballot(v != 0);
    if (lane == 0) out[base >> 6] = bb;
  }
}

// ---------------- LDS-staged QKV GEMM: X[8192,768] @ W[2304,768]^T + b ----------
__global__ __launch_bounds__(256) void gemm_qkv(
    const unsigned short* __restrict__ X,
    const unsigned short* __restrict__ W,
    const float* __restrict__ bias,
    unsigned short* __restrict__ Qd,
    unsigned short* __restrict__ Kd,
    unsigned short* __restrict__ Vd)
{
  __shared__ unsigned short As[128*40];
  __shared__ unsigned short Bs[128*40];
  const int K = 768;
  int tid = threadIdx.x;
  int bm = blockIdx.x & 63;
  int bn = blockIdx.x >> 6;
  int wave = tid >> 6, lane = tid & 63;
  int lo = lane & 15, g = lane >> 4;
  int wr = (wave >> 1) * 64, wc = (wave & 1) * 64;
  int row0 = bm * 128, col0 = bn * 128;

  int sr = tid >> 1;
  int sc = (tid & 1) * 16;
  const unsigned short* gA = X + (size_t)(row0 + sr) * K + sc;
  const unsigned short* gB = W + (size_t)(col0 + sr) * K + sc;
  unsigned short* sA = &As[sr * 40 + sc];
  unsigned short* sB = &Bs[sr * 40 + sc];

  f32x4 acc[4][4] = {};
  for (int k0 = 0; k0 < K; k0 += 32) {
    bf16x8 a0 = *(const bf16x8*)(gA + k0);
    bf16x8 a1 = *(const bf16x8*)(gA + k0 + 8);
    bf16x8 b0 = *(const bf16x8*)(gB + k0);
    bf16x8 b1 = *(const bf16x8*)(gB + k0 + 8);
    __syncthreads();
    *(bf16x8*)(sA)     = a0;
    *(bf16x8*)(sA + 8) = a1;
    *(bf16x8*)(sB)     = b0;
    *(bf16x8*)(sB + 8) = b1;
    __syncthreads();
    bf16x8 af[4], bf[4];
#pragma unroll
    for (int i = 0; i < 4; ++i) af[i] = *(const bf16x8*)&As[(wr + i*16 + lo)*40 + g*8];
#pragma unroll
    for (int i = 0; i < 4; ++i) bf[i] = *(const bf16x8*)&Bs[(wc + i*16 + lo)*40 + g*8];
#pragma unroll
    for (int mi = 0; mi < 4; ++mi)
#pragma unroll
      for (int ni = 0; ni < 4; ++ni)
        acc[mi][ni] = MFMA32(af[mi], bf[ni], acc[mi][ni]);
  }
  int orow0 = row0 + wr, ocol0 = col0 + wc;
#pragma unroll
  for (int ni = 0; ni < 4; ++ni) {
    int col = ocol0 + ni*16 + lo;
    float bc = bias[col];
    int which = col / 768;
    int rem = col - which * 768;
    int h = rem >> 6, d = rem & 63;
    unsigned short* dst = (which == 0) ? Qd : (which == 1) ? Kd : Vd;
    float scale = (which == 0) ? 0.125f : 1.0f;
#pragma unroll
    for (int mi = 0; mi < 4; ++mi) {
#pragma unroll
      for (int r = 0; r < 4; ++r) {
        int row = orow0 + mi*16 + g*4 + r;
        int bb = row >> 10, n = row & 1023;
        dst[(((size_t)bb*12 + h)*1024 + n)*64 + d] = f2bf((acc[mi][ni][r] + bc) * scale);
      }
    }
  }
}

// ---------------- V transpose: [96][1024][64] -> [96][64][1024] ----------------
__global__ __launch_bounds__(256) void vtrans(const unsigned short* __restrict__ V,
                                              unsigned short* __restrict__ Vt){
  __shared__ unsigned short t[64][72];
  int bh = blockIdx.y;
  int n0 = blockIdx.x * 64;
  int tid = threadIdx.x;
  int nl = tid >> 2;
  int dq = (tid & 3) * 16;
  const unsigned short* src = V + ((size_t)bh*1024 + n0 + nl)*64 + dq;
  bf16x8 a0 = *(const bf16x8*)(src);
  bf16x8 a1 = *(const bf16x8*)(src + 8);
  *(bf16x8*)&t[nl][dq]     = a0;
  *(bf16x8*)&t[nl][dq + 8] = a1;
  __syncthreads();
  int d  = tid >> 2;
  int nq = (tid & 3) * 16;
  union { unsigned short s[16]; bf16x8 v[2]; } pk;
#pragma unroll
  for (int j = 0; j < 16; ++j) pk.s[j] = t[nq + j][d];
  unsigned short* dst = Vt + ((size_t)bh*64 + d)*1024 + n0 + nq;
  *(bf16x8*)(dst)     = pk.v[0];
  *(bf16x8*)(dst + 8) = pk.v[1];
}

// ---------------- fused attention core, 8 waves, LDS-shared K/V ----------------
// grid (8 qblocks, 96); block 512 = 8 waves x 16 q-rows; KVBLK=64 double-buffered.
// Counted-vmcnt barrier: only staged loads must retire; NT out1 stores drift
// across the barrier (T4). setprio around MFMA clusters (T5).
__global__ __launch_bounds__(512, 4) void attn_kernel(
    const unsigned short* __restrict__ Qd,
    const unsigned short* __restrict__ Kd,
    const unsigned short* __restrict__ Vt,     // [96][64][1024]
    const float* __restrict__ bias,            // [12,1024,1024] fp32
    const unsigned* __restrict__ maskbits,     // [8*1024][32] u32 words
    float* __restrict__ out1,                  // [96,1024,1024] fp32
    unsigned short* __restrict__ ctx)          // [8192,768] bf16
{
  __shared__ char lds[32768];
  const int N = 1024, D = 64;
  int y = blockIdx.y;
  int h = y >> 3, bb = y & 7;
  int bh = bb * 12 + h;
  int tid = threadIdx.x;
  int wave = tid >> 6, lane = tid & 63;
  int lo = lane & 15, g = lane >> 4;
  int qrow = blockIdx.x * 128 + wave * 16 + lo;

  const size_t qoff = ((size_t)bh * N + qrow) * D;
  bf16x8 qf0 = *(const bf16x8*)(Qd + qoff + g*8);
  bf16x8 qf1 = *(const bf16x8*)(Qd + qoff + 32 + g*8);

  const float* bias_row = bias + ((size_t)h * N + qrow) * N;
  const unsigned* mrow  = maskbits + ((size_t)bb * N + qrow) * 32;
  float* out_row        = out1 + ((size_t)bh * N + qrow) * N;

  // staging: thread t fills lds byte o=t*16; content = tile[swz(o)] so that
  // reading phys=swz(logical) returns tile[logical].
  int o  = tid * 16;
  int sw = o ^ (((o >> 7) & 7) << 4);
  const char* kbase = (const char*)(Kd + (size_t)bh * N * D);
  const char* vbase = (const char*)(Vt + (size_t)bh * D * N);
  const char* ksrc  = kbase + sw;                           // + kv*128 per tile
  const char* vsrc  = vbase + (o >> 7) * 2048 + (sw & 127); // + kv*2 per tile
  int wbase = (tid >> 6) << 10;                             // wave-uniform LDS base

#define STAGE(buf, kv) do { \
    __builtin_amdgcn_global_load_lds( \
      (const __attribute__((address_space(1))) unsigned*)(ksrc + (size_t)(kv)*128), \
      (__attribute__((address_space(3))) unsigned*)(lds + (buf)*8192 + wbase), 16, 0, 0); \
    __builtin_amdgcn_global_load_lds( \
      (const __attribute__((address_space(1))) unsigned*)(vsrc + (size_t)(kv)*2), \
      (__attribute__((address_space(3))) unsigned*)(lds + 16384 + (buf)*8192 + wbase), 16, 0, 0); \
  } while (0)

#define SWZ(lb) ((lb) ^ ((((lb) >> 7) & 7) << 4))

  float m_run = -INFINITY, l_part = 0.0f;
  f32x4 oacc[4] = {};   // O^T: lane holds q=lo, d = c*16 + g*4 + reg

  STAGE(0, 0);
  __syncthreads();      // prologue: full drain (no stores outstanding yet)
  int cur = 0;

  for (int it = 0; it < 16; ++it) {
    int kv = it * 64;
    // STAGE first so the staged loads are the OLDEST vmem ops of this iter
    if (it < 15) STAGE(cur ^ 1, kv + 64);
    __builtin_amdgcn_sched_barrier(0);   // pin: stage stays oldest

    unsigned mw0 = mrow[it*2];
    unsigned mw1 = mrow[it*2 + 1];

    // QK^T over 4 sub-tiles of 16 kpos: s[sub][r] = S[q=lo][kv + sub*16 + g*4 + r]
    f32x4 s[4];
    __builtin_amdgcn_s_setprio(1);
#pragma unroll
    for (int sub = 0; sub < 4; ++sub) {
      int lbr = (sub*16 + lo) * 128 + g*16;
      bf16x8 k0 = *(const bf16x8*)(lds + cur*8192 + SWZ(lbr));
      bf16x8 k1 = *(const bf16x8*)(lds + cur*8192 + SWZ(lbr + 64));
      f32x4 t = {};
      t = MFMA32(k0, qf0, t);
      t = MFMA32(k1, qf1, t);
      s[sub] = t;
    }
    __builtin_amdgcn_s_setprio(0);

    // mask (bits) + bias + out1 dump
    float sp[16];
#pragma unroll
    for (int sub = 0; sub < 4; ++sub) {
      f32x4 bi = *(const f32x4*)(bias_row + kv + sub*16 + g*4);
      unsigned mw = (sub < 2) ? mw0 : mw1;
      int sh = (sub & 1) * 16 + g * 4;
#pragma unroll
      for (int r = 0; r < 4; ++r)
        sp[sub*4+r] = (((mw >> (sh + r)) & 1u) ? NEGV : s[sub][r]) + bi[r];
      f32x4 ov;
      ov[0] = sp[sub*4]; ov[1] = sp[sub*4+1]; ov[2] = sp[sub*4+2]; ov[3] = sp[sub*4+3];
      __builtin_nontemporal_store(ov, (f32x4*)(out_row + kv + sub*16 + g*4));
    }

    // deferred-max online softmax
    float lmax = sp[0];
#pragma unroll
    for (int i = 1; i < 16; ++i) lmax = fmaxf(lmax, sp[i]);
    if (!__all(lmax <= m_run + 8.0f)) {
      float tmax = fmaxf(lmax, __shfl_xor(lmax, 16));
      tmax = fmaxf(tmax, __shfl_xor(tmax, 32));
      float mnew = fmaxf(m_run, tmax);
      float alpha = __expf(m_run - mnew);
      l_part *= alpha;
#pragma unroll
      for (int c = 0; c < 4; ++c) {
        oacc[c][0] *= alpha; oacc[c][1] *= alpha;
        oacc[c][2] *= alpha; oacc[c][3] *= alpha;
      }
      m_run = mnew;
    }
    float lsum = 0.0f;
#pragma unroll
    for (int i = 0; i < 16; ++i) { sp[i] = __expf(sp[i] - m_run); lsum += sp[i]; }
    l_part += lsum;

    union { unsigned u[2]; bf16x4 h; } pk[4];
#pragma unroll
    for (int ks = 0; ks < 4; ++ks) {
      pk[ks].u[0] = cvtpk(sp[ks*4],   sp[ks*4+1]);
      pk[ks].u[1] = cvtpk(sp[ks*4+2], sp[ks*4+3]);
    }

    // PV: oacc[c] += Vs[d=c*16+lo][k=ks*16+g*4+e] x P
    __builtin_amdgcn_s_setprio(1);
#pragma unroll
    for (int ks = 0; ks < 4; ++ks)
#pragma unroll
      for (int c = 0; c < 4; ++c) {
        int lbv = (c*16 + lo) * 128 + ks*32 + g*8;
        bf16x4 vf = *(const bf16x4*)(lds + 16384 + cur*8192 + SWZ(lbv));
        oacc[c] = MFMA16(vf, pk[ks].h, oacc[c]);
      }
    __builtin_amdgcn_s_setprio(0);

    cur ^= 1;
    // counted barrier: retire everything except the <=4 newest (the NT stores).
    // Staged loads are oldest -> guaranteed retired; lgkm drained by MFMA use.
    __builtin_amdgcn_sched_barrier(0);
    asm volatile("s_waitcnt vmcnt(4)" ::: "memory");
    __builtin_amdgcn_s_barrier();
  }

  l_part += __shfl_xor(l_part, 16);
  l_part += __shfl_xor(l_part, 32);
  float inv = 1.0f / l_part;

  size_t crow = ((size_t)bb * N + qrow) * 768 + h * 64;
#pragma unroll
  for (int c = 0; c < 4; ++c) {
    ushort4 u;
    u.x = f2bf(oacc[c][0] * inv);
    u.y = f2bf(oacc[c][1] * inv);
    u.z = f2bf(oacc[c][2] * inv);
    u.w = f2bf(oacc[c][3] * inv);
    *(ushort4*)(ctx + crow + c*16 + g*4) = u;
  }
#undef STAGE
#undef SWZ
}

// ---------------- LDS-staged proj GEMM: ctx[8192,768] @ Wp[768,768]^T + b ------
__global__ __launch_bounds__(256) void gemm_proj(
    const unsigned short* __restrict__ X,
    const unsigned short* __restrict__ W,
    const float* __restrict__ bias,
    float* __restrict__ out)
{
  __shared__ unsigned short As[128*40];
  __shared__ unsigned short Bs[128*40];
  const int K = 768;
  int tid = threadIdx.x;
  int bm = blockIdx.x & 63;
  int bn = blockIdx.x >> 6;
  int wave = tid >> 6, lane = tid & 63;
  int lo = lane & 15, g = lane >> 4;
  int wr = (wave >> 1) * 64, wc = (wave & 1) * 64;
  int row0 = bm * 128, col0 = bn * 128;

  int sr = tid >> 1;
  int sc = (tid & 1) * 16;
  const unsigned short* gA = X + (size_t)(row0 + sr) * K + sc;
  const unsigned short* gB = W + (size_t)(col0 + sr) * K + sc;
  unsigned short* sA = &As[sr * 40 + sc];
  unsigned short* sB = &Bs[sr * 40 + sc];

  f32x4 acc[4][4] = {};
  for (int k0 = 0; k0 < K; k0 += 32) {
    bf16x8 a0 = *(const bf16x8*)(gA + k0);
    bf16x8 a1 = *(const bf16x8*)(gA + k0 + 8);
    bf16x8 b0 = *(const bf16x8*)(gB + k0);
    bf16x8 b1 = *(const bf16x8*)(gB + k0 + 8);
    __syncthreads();
    *(bf16x8*)(sA)     = a0;
    *(bf16x8*)(sA + 8) = a1;
    *(bf16x8*)(sB)     = b0;
    *(bf16x8*)(sB + 8) = b1;
    __syncthreads();
    bf16x8 af[4], bf[4];
#pragma unroll
    for (int i = 0; i < 4; ++i) af[i] = *(const bf16x8*)&As[(wr + i*16 + lo)*40 + g*8];
#pragma unroll
    for (int i = 0; i < 4; ++i) bf[i] = *(const bf16x8*)&Bs[(wc + i*16 + lo)*40 + g*8];
#pragma unroll
    for (int mi = 0; mi < 4; ++mi)
#pragma unroll
      for (int ni = 0; ni < 4; ++ni)
        acc[mi][ni] = MFMA32(af[mi], bf[ni], acc[mi][ni]);
  }
  int orow0 = row0 + wr, ocol0 = col0 + wc;
#pragma unroll
  for (int ni = 0; ni < 4; ++ni) {
    int col = ocol0 + ni*16 + lo;
    float bc = bias[col];
#pragma unroll
    for (int mi = 0; mi < 4; ++mi) {
#pragma unroll
      for (int r = 0; r < 4; ++r) {
        int row = orow0 + mi*16 + g*4 + r;
        out[(size_t)row * 768 + col] = acc[mi][ni][r] + bc;
      }
    }
  }
}

extern "C" void kernel_launch(void* const* d_in, const int* in_sizes, int n_in,
                              void* d_out, int out_size, void* d_ws, size_t ws_size,
                              hipStream_t stream) {
  const float* x            = (const float*)d_in[0];
  const float* rel_pos_bias = (const float*)d_in[1];
  const int* mask           = (const int*)d_in[2];
  const float* Wqkv         = (const float*)d_in[3];
  const float* bqkv         = (const float*)d_in[4];
  const float* Wproj        = (const float*)d_in[5];
  const float* bproj        = (const float*)d_in[6];

  float* out0 = (float*)d_out;                         // [8,1024,768]
  float* out1 = out0 + (size_t)8 * 1024 * 768;         // [8,12,1024,1024]

  char* ws = (char*)d_ws;
  unsigned short* xb  = (unsigned short*)(ws);            // dead after gemm_qkv -> Vt
  unsigned short* wqb = (unsigned short*)(ws + 12582912); // dead after gemm_qkv -> maskbits
  unsigned short* wpb = (unsigned short*)(ws + 16121856);
  unsigned short* Qb  = (unsigned short*)(ws + 17301504);
  unsigned short* Kb  = (unsigned short*)(ws + 29884416);
  unsigned short* Vb  = (unsigned short*)(ws + 42467328);
  unsigned short* ctx = (unsigned short*)(ws + 55050240);
  unsigned short* Vtb = xb;
  unsigned long long* mbits = (unsigned long long*)(ws + 12582912);

  cvt_all<<<8448, 256, 0, stream>>>(x, Wqkv, Wproj, xb);

  gemm_qkv<<<1152, 256, 0, stream>>>(xb, wqb, bqkv, Qb, Kb, Vb);

  mask_to_bits<<<2048, 256, 0, stream>>>(mask, mbits);

  vtrans<<<dim3(16, 96), 256, 0, stream>>>(Vb, Vtb);

  attn_kernel<<<dim3(8, 96), 512, 0, stream>>>(Qb, Kb, Vtb, rel_pos_bias,
                                               (const unsigned*)mbits, out1, ctx);

  gemm_proj<<<384, 256, 0, stream>>>(ctx, wpb, bproj, out0);
}